// Round 1
// baseline (497.832 us; speedup 1.0000x reference)
//
#include <hip/hip_runtime.h>
#include <math.h>

#define BB 2
#define LL 1024
#define CCH 512
#define HH 8
#define DD 64
#define LN_EPSF 1e-5f

__device__ __forceinline__ float wave_max(float v) {
#pragma unroll
  for (int off = 32; off > 0; off >>= 1) v = fmaxf(v, __shfl_xor(v, off));
  return v;
}
__device__ __forceinline__ float wave_sum(float v) {
#pragma unroll
  for (int off = 32; off > 0; off >>= 1) v += __shfl_xor(v, off);
  return v;
}

// ---------------- LayerNorm: one block per row of 512 ----------------
__global__ __launch_bounds__(256) void ln_kernel(const float* __restrict__ f,
                                                 const float* __restrict__ g,
                                                 const float* __restrict__ bta,
                                                 float* __restrict__ x) {
  const int row = blockIdx.x;
  const int tid = threadIdx.x;
  const int wave = tid >> 6, lane = tid & 63;
  __shared__ float red[8];
  const float* fr = f + (size_t)row * CCH;
  float2 v = *(const float2*)&fr[tid * 2];
  float s = wave_sum(v.x + v.y);
  if (lane == 0) red[wave] = s;
  __syncthreads();
  float mu = (red[0] + red[1] + red[2] + red[3]) * (1.0f / CCH);
  float dx = v.x - mu, dy = v.y - mu;
  float sq = wave_sum(dx * dx + dy * dy);
  if (lane == 0) red[4 + wave] = sq;
  __syncthreads();
  float var = (red[4] + red[5] + red[6] + red[7]) * (1.0f / CCH);
  float inv = 1.0f / sqrtf(var + LN_EPSF);
  float2 gg = *(const float2*)&g[tid * 2];
  float2 bb = *(const float2*)&bta[tid * 2];
  float2 o;
  o.x = dx * inv * gg.x + bb.x;
  o.y = dy * inv * gg.y + bb.y;
  *(float2*)&x[(size_t)row * CCH + tid * 2] = o;
}

// ---------------- Generic fp32 GEMM + bias: C[M,N] = A[M,K] @ B[K,N] + b ----------------
// 64x64 tile per block of 256 threads, 4x4 microtile per thread, K-tile 16.
__global__ __launch_bounds__(256) void gemm_bias(const float* __restrict__ A,
                                                 const float* __restrict__ Bm,
                                                 const float* __restrict__ bias,
                                                 float* __restrict__ Cm,
                                                 int M, int N, int K) {
  __shared__ float As[16][64];  // [k][m]
  __shared__ float Bs[16][64];  // [k][n]
  const int tid = threadIdx.x;
  const int tm = tid & 15, tn = tid >> 4;
  const int m0 = blockIdx.y * 64, n0 = blockIdx.x * 64;
  float acc[4][4] = {};
  const int arow = tid >> 2, akq = tid & 3;
  const int bk = tid >> 4, bn4 = tid & 15;
  for (int k0 = 0; k0 < K; k0 += 16) {
    float4 a4 = *(const float4*)&A[(size_t)(m0 + arow) * K + k0 + akq * 4];
    As[akq * 4 + 0][arow] = a4.x;
    As[akq * 4 + 1][arow] = a4.y;
    As[akq * 4 + 2][arow] = a4.z;
    As[akq * 4 + 3][arow] = a4.w;
    int n = n0 + bn4 * 4;
    float4 b4;
    if (n + 3 < N) {
      b4 = *(const float4*)&Bm[(size_t)(k0 + bk) * N + n];
    } else {
      b4.x = (n + 0 < N) ? Bm[(size_t)(k0 + bk) * N + n + 0] : 0.f;
      b4.y = (n + 1 < N) ? Bm[(size_t)(k0 + bk) * N + n + 1] : 0.f;
      b4.z = (n + 2 < N) ? Bm[(size_t)(k0 + bk) * N + n + 2] : 0.f;
      b4.w = (n + 3 < N) ? Bm[(size_t)(k0 + bk) * N + n + 3] : 0.f;
    }
    *(float4*)&Bs[bk][bn4 * 4] = b4;
    __syncthreads();
#pragma unroll
    for (int kk = 0; kk < 16; ++kk) {
      float4 av = *(const float4*)&As[kk][tm * 4];
      float4 bv = *(const float4*)&Bs[kk][tn * 4];
      acc[0][0] += av.x * bv.x; acc[0][1] += av.x * bv.y;
      acc[0][2] += av.x * bv.z; acc[0][3] += av.x * bv.w;
      acc[1][0] += av.y * bv.x; acc[1][1] += av.y * bv.y;
      acc[1][2] += av.y * bv.z; acc[1][3] += av.y * bv.w;
      acc[2][0] += av.z * bv.x; acc[2][1] += av.z * bv.y;
      acc[2][2] += av.z * bv.z; acc[2][3] += av.z * bv.w;
      acc[3][0] += av.w * bv.x; acc[3][1] += av.w * bv.y;
      acc[3][2] += av.w * bv.z; acc[3][3] += av.w * bv.w;
    }
    __syncthreads();
  }
#pragma unroll
  for (int i = 0; i < 4; ++i) {
    int m = m0 + tm * 4 + i;
#pragma unroll
    for (int j = 0; j < 4; ++j) {
      int n = n0 + tn * 4 + j;
      if (n < N) Cm[(size_t)m * N + n] = acc[i][j] + bias[n];
    }
  }
}

// ---------------- Fused flash-style IPA attention ----------------
// grid: (L/64 Q-tiles, B*H). block: 256 = 4 waves; wave w owns Q rows [w*16, w*16+16).
// lane = key index (scores) or d index (O update).
__global__ __launch_bounds__(256) void ipa_attn(
    const float* __restrict__ qsg, const float* __restrict__ ksg,
    const float* __restrict__ vsg, const float* __restrict__ qpg,
    const float* __restrict__ kpg, const float* __restrict__ pscale,
    float* __restrict__ outs) {
  const int qt = blockIdx.x;
  const int bh = blockIdx.y;
  const int b = bh >> 3, h = bh & 7;
  const int tid = threadIdx.x;
  const int wave = tid >> 6, lane = tid & 63;
  const float ps_h = pscale[h];

  __shared__ float q_t[64][64];     // Q^T [d][row], pre-scaled by 1/8
  __shared__ float qp_t[12][64];    // Qp^T [c][row], pre-scaled by 2*ps_h
  __shared__ float qsq_l[64];       // ps_h * |qp|^2 per row
  __shared__ float kv[64 * 64];     // K as [d][j] (transposed), then V as [j][d]
  __shared__ float kp_l[64][13];    // Kp [j][c] raw (pad 13: conflict-free)
  __shared__ float ksq_l[64];       // ps_h * |kp|^2 per key
  __shared__ float p_t[4][64][20];  // per-wave P [j][r] (stride 20: 16B-aligned rows)

  const int i0 = qt * 64;
// init Q tiles (scales folded in)
#pragma unroll
  for (int c = 0; c < 4; ++c) {
    int e = c * 256 + tid;
    int row = e >> 4, d4 = e & 15;
    float4 q4 = *(const float4*)&qsg[((size_t)(b * LL + i0 + row)) * CCH + h * DD + d4 * 4];
    q_t[d4 * 4 + 0][row] = q4.x * 0.125f;
    q_t[d4 * 4 + 1][row] = q4.y * 0.125f;
    q_t[d4 * 4 + 2][row] = q4.z * 0.125f;
    q_t[d4 * 4 + 3][row] = q4.w * 0.125f;
  }
  if (tid < 64) {
    const float* qpr = &qpg[((size_t)(b * LL + i0 + tid)) * 96 + h * 12];
    float acc = 0.f;
#pragma unroll
    for (int c = 0; c < 12; ++c) {
      float v = qpr[c];
      qp_t[c][tid] = v * (2.f * ps_h);
      acc += v * v;
    }
    qsq_l[tid] = ps_h * acc;
  }

  float O[16], m[16], l[16];
#pragma unroll
  for (int r = 0; r < 16; ++r) { O[r] = 0.f; m[r] = -INFINITY; l[r] = 0.f; }

  for (int kt = 0; kt < 16; ++kt) {
    const int j0 = kt * 64;
    __syncthreads();  // prev-tile V reads done (also covers Q-init visibility at kt=0)
// load K transposed into kv[d][j]
#pragma unroll
    for (int c = 0; c < 4; ++c) {
      int e = c * 256 + tid;
      int row = e >> 4, d4 = e & 15;
      float4 k4 = *(const float4*)&ksg[((size_t)(b * LL + j0 + row)) * CCH + h * DD + d4 * 4];
      kv[(d4 * 4 + 0) * 64 + row] = k4.x;
      kv[(d4 * 4 + 1) * 64 + row] = k4.y;
      kv[(d4 * 4 + 2) * 64 + row] = k4.z;
      kv[(d4 * 4 + 3) * 64 + row] = k4.w;
    }
    if (tid < 64) {
      const float* kpr = &kpg[((size_t)(b * LL + j0 + tid)) * 96 + h * 12];
      float acc = 0.f;
#pragma unroll
      for (int c = 0; c < 12; ++c) {
        float v = kpr[c];
        kp_l[tid][c] = v;
        acc += v * v;
      }
      ksq_l[tid] = ps_h * acc;
    }
    __syncthreads();

    // scores: lane = key j; accumulate 0.125*q.k + 2*ps_h*qp.kp
    float s[16];
#pragma unroll
    for (int r = 0; r < 16; ++r) s[r] = 0.f;
    for (int d = 0; d < 64; ++d) {
      float kd = kv[d * 64 + lane];
      const float4* qrow = (const float4*)&q_t[d][wave * 16];
#pragma unroll
      for (int r4 = 0; r4 < 4; ++r4) {
        float4 q4 = qrow[r4];
        s[r4 * 4 + 0] += q4.x * kd;
        s[r4 * 4 + 1] += q4.y * kd;
        s[r4 * 4 + 2] += q4.z * kd;
        s[r4 * 4 + 3] += q4.w * kd;
      }
    }
#pragma unroll
    for (int c = 0; c < 12; ++c) {
      float kpc = kp_l[lane][c];
      const float4* qprow = (const float4*)&qp_t[c][wave * 16];
#pragma unroll
      for (int r4 = 0; r4 < 4; ++r4) {
        float4 q4 = qprow[r4];
        s[r4 * 4 + 0] += q4.x * kpc;
        s[r4 * 4 + 1] += q4.y * kpc;
        s[r4 * 4 + 2] += q4.z * kpc;
        s[r4 * 4 + 3] += q4.w * kpc;
      }
    }
    {
      float ksq_j = ksq_l[lane];
      const float4* qq4 = (const float4*)&qsq_l[wave * 16];
#pragma unroll
      for (int r4 = 0; r4 < 4; ++r4) {
        float4 qv = qq4[r4];
        s[r4 * 4 + 0] -= qv.x + ksq_j;
        s[r4 * 4 + 1] -= qv.y + ksq_j;
        s[r4 * 4 + 2] -= qv.z + ksq_j;
        s[r4 * 4 + 3] -= qv.w + ksq_j;
      }
    }
// online softmax (rows private to wave; m/l replicated across lanes)
#pragma unroll
    for (int r = 0; r < 16; ++r) {
      float mt = wave_max(s[r]);
      float mnew = fmaxf(m[r], mt);
      float p = __expf(s[r] - mnew);
      float alpha = __expf(m[r] - mnew);
      l[r] = l[r] * alpha + wave_sum(p);
      O[r] *= alpha;
      m[r] = mnew;
      p_t[wave][lane][r] = p;
    }
    __syncthreads();  // all waves done reading K
// load V natural into kv[j][d]
#pragma unroll
    for (int c = 0; c < 4; ++c) {
      int e = c * 256 + tid;
      int row = e >> 4, d4 = e & 15;
      *(float4*)&kv[row * 64 + d4 * 4] =
          *(const float4*)&vsg[((size_t)(b * LL + j0 + row)) * CCH + h * DD + d4 * 4];
    }
    __syncthreads();
    // O update: lane = d
    for (int j = 0; j < 64; ++j) {
      float v = kv[j * 64 + lane];
      const float4* prow = (const float4*)&p_t[wave][j][0];
#pragma unroll
      for (int r4 = 0; r4 < 4; ++r4) {
        float4 p4 = prow[r4];
        O[r4 * 4 + 0] += p4.x * v;
        O[r4 * 4 + 1] += p4.y * v;
        O[r4 * 4 + 2] += p4.z * v;
        O[r4 * 4 + 3] += p4.w * v;
      }
    }
  }
#pragma unroll
  for (int r = 0; r < 16; ++r) {
    int i = i0 + wave * 16 + r;
    outs[((size_t)(b * LL + i)) * CCH + h * DD + lane] = O[r] / l[r];
  }
}

extern "C" void kernel_launch(void* const* d_in, const int* in_sizes, int n_in,
                              void* d_out, int out_size, void* d_ws, size_t ws_size,
                              hipStream_t stream) {
  (void)in_sizes; (void)n_in; (void)out_size; (void)ws_size;
  const float* features = (const float*)d_in[0];
  // d_in[1] = coords: unused by reference
  const float* ln_g = (const float*)d_in[2];
  const float* ln_b = (const float*)d_in[3];
  const float* wq = (const float*)d_in[4];
  const float* bq = (const float*)d_in[5];
  const float* wk = (const float*)d_in[6];
  const float* bk = (const float*)d_in[7];
  const float* wv = (const float*)d_in[8];
  const float* bv = (const float*)d_in[9];
  const float* wqp = (const float*)d_in[10];
  const float* bqp = (const float*)d_in[11];
  const float* wkp = (const float*)d_in[12];
  const float* bkp = (const float*)d_in[13];
  // d_in[14]/d_in[15] = wvp/bvp: unused by reference
  const float* wo = (const float*)d_in[16];
  const float* bo = (const float*)d_in[17];
  const float* pscale = (const float*)d_in[18];
  float* out = (float*)d_out;
  float* ws = (float*)d_ws;

  const size_t NTOK = (size_t)BB * LL;  // 2048
  float* x = ws;
  float* qsb = x + NTOK * CCH;
  float* ksb = qsb + NTOK * CCH;
  float* vsb = ksb + NTOK * CCH;
  float* qpb = vsb + NTOK * CCH;
  float* kpb = qpb + NTOK * 96;
  float* outsb = kpb + NTOK * 96;  // total ws use ~21.5 MB

  ln_kernel<<<dim3((unsigned)NTOK), 256, 0, stream>>>(features, ln_g, ln_b, x);

  dim3 g512(512 / 64, (unsigned)(NTOK / 64));
  dim3 g96(2, (unsigned)(NTOK / 64));
  gemm_bias<<<g512, 256, 0, stream>>>(x, wq, bq, qsb, (int)NTOK, 512, 512);
  gemm_bias<<<g512, 256, 0, stream>>>(x, wk, bk, ksb, (int)NTOK, 512, 512);
  gemm_bias<<<g512, 256, 0, stream>>>(x, wv, bv, vsb, (int)NTOK, 512, 512);
  gemm_bias<<<g96, 256, 0, stream>>>(x, wqp, bqp, qpb, (int)NTOK, 96, 512);
  gemm_bias<<<g96, 256, 0, stream>>>(x, wkp, bkp, kpb, (int)NTOK, 96, 512);

  dim3 ga(LL / 64, BB * HH);
  ipa_attn<<<ga, 256, 0, stream>>>(qsb, ksb, vsb, qpb, kpb, pscale, outsb);

  gemm_bias<<<g512, 256, 0, stream>>>(outsb, wo, bo, out, (int)NTOK, 512, 512);
}